// Round 3
// baseline (546.159 us; speedup 1.0000x reference)
//
#include <hip/hip_runtime.h>

#define B_ 64
#define N_ 4096
#define C_ 10
#define D_ 8
#define E_ 16
#define EPS_ 1e-7f

__device__ inline float reduce16(float v) {
    v += __shfl_xor(v, 1);
    v += __shfl_xor(v, 2);
    v += __shfl_xor(v, 4);
    v += __shfl_xor(v, 8);
    return v;
}

// Block: 512 threads = 8 waves, owns n-tile of 2*np and ALL 64 b.
// Wave w: b-quarter (w&3), n-half (w>>2). Lane: eq = lane&3 (e-quad),
// bl = lane>>2 (b within quarter). W-load addresses vary only with eq ->
// one 64B line per wave instruction (16-way lane broadcast of W across b).
template <bool UNIFORM>
__global__ __launch_bounds__(512, 2) void caps_pass(
    const float* __restrict__ x, const float* __restrict__ W,
    const float* __restrict__ v_cum, float* __restrict__ partial,
    int np)
{
    const int tid  = (int)threadIdx.x;
    const int w    = tid >> 6;
    const int lane = tid & 63;
    const int eq   = lane & 3;
    const int bl   = lane >> 2;
    const int b    = (w & 3) * 16 + bl;
    const int p    = w >> 2;
    const int n0   = (int)blockIdx.x * (2 * np) + p * np;

    float4 vc[C_];
    if (!UNIFORM) {
#pragma unroll
        for (int c = 0; c < C_; ++c)
            vc[c] = *(const float4*)(v_cum + (b * C_ + c) * E_ + eq * 4);
    }

    float4 acc[C_];
#pragma unroll
    for (int c = 0; c < C_; ++c) acc[c] = make_float4(0.f, 0.f, 0.f, 0.f);

    for (int i = 0; i < np; ++i) {
        const int n = n0 + i;
        const float4* xp = (const float4*)(x + ((size_t)b * N_ + n) * D_);
        const float4 x0 = xp[0], x1 = xp[1];
        const float xv[D_] = {x0.x, x0.y, x0.z, x0.w, x1.x, x1.y, x1.z, x1.w};
        const float4* Wn = (const float4*)(W + (size_t)n * (C_ * D_ * E_)) + eq;

        float4 uh[C_];
#pragma unroll
        for (int c = 0; c < C_; ++c) {
            float4 u = make_float4(0.f, 0.f, 0.f, 0.f);
#pragma unroll
            for (int d = 0; d < D_; ++d) {
                const float4 wq = Wn[(c * D_ + d) * 4];
                u.x = fmaf(xv[d], wq.x, u.x);
                u.y = fmaf(xv[d], wq.y, u.y);
                u.z = fmaf(xv[d], wq.z, u.z);
                u.w = fmaf(xv[d], wq.w, u.w);
            }
            uh[c] = u;
        }

        float wgt[C_];
        if (UNIFORM) {
#pragma unroll
            for (int c = 0; c < C_; ++c) wgt[c] = 0.1f;
        } else {
            float logit[C_];
#pragma unroll
            for (int c = 0; c < C_; ++c) {
                float t = uh[c].x * vc[c].x + uh[c].y * vc[c].y +
                          uh[c].z * vc[c].z + uh[c].w * vc[c].w;
                t += __shfl_xor(t, 1);
                t += __shfl_xor(t, 2);
                logit[c] = t;
            }
            float m = logit[0];
#pragma unroll
            for (int c = 1; c < C_; ++c) m = fmaxf(m, logit[c]);
            float ss = 0.f;
#pragma unroll
            for (int c = 0; c < C_; ++c) { wgt[c] = __expf(logit[c] - m); ss += wgt[c]; }
            const float inv = 1.f / ss;
#pragma unroll
            for (int c = 0; c < C_; ++c) wgt[c] *= inv;
        }

#pragma unroll
        for (int c = 0; c < C_; ++c) {
            acc[c].x = fmaf(wgt[c], uh[c].x, acc[c].x);
            acc[c].y = fmaf(wgt[c], uh[c].y, acc[c].y);
            acc[c].z = fmaf(wgt[c], uh[c].z, acc[c].z);
            acc[c].w = fmaf(wgt[c], uh[c].w, acc[c].w);
        }
    }

    // per-wave partial: partial[slot][b][c*16+e]
    const int slot = (int)blockIdx.x * 2 + p;
    float* dst = partial + ((size_t)slot * B_ + b) * (C_ * E_) + eq * 4;
#pragma unroll
    for (int c = 0; c < C_; ++c)
        *(float4*)(dst + c * E_) = acc[c];
}

// Block per b: sum partials over NS slots, squash, write v_cum/out.
// mode: 0 = v_cum = v (first), 1 = v_cum += v, 2 = out = v (last)
__global__ __launch_bounds__(512) void caps_reduce(
    const float* __restrict__ partial, float* __restrict__ v_cum,
    float* __restrict__ out, int NS, int mode)
{
    const int b = (int)blockIdx.x;
    const int tid = (int)threadIdx.x;
    const int half = tid >> 8;
    const int ce = tid & 255;
    __shared__ float red[2][C_ * E_];
    if (ce < C_ * E_) {
        const int per = NS >> 1;
        float s = 0.f;
        for (int k = 0; k < per; ++k) {
            const int slot = half * per + k;
            s += partial[((size_t)slot * B_ + b) * (C_ * E_) + ce];
        }
        red[half][ce] = s;
    }
    __syncthreads();
    if (half == 0 && ce < C_ * E_) {
        float s = red[0][ce] + red[1][ce];
        const float s2 = reduce16(s * s);
        const float scale = (s2 / (1.f + s2)) * rsqrtf(s2 + EPS_);
        const float v = scale * s;
        if (mode == 2)      out[b * (C_ * E_) + ce] = v;
        else if (mode == 0) v_cum[b * (C_ * E_) + ce] = v;
        else                v_cum[b * (C_ * E_) + ce] += v;
    }
}

extern "C" void kernel_launch(void* const* d_in, const int* in_sizes, int n_in,
                              void* d_out, int out_size, void* d_ws, size_t ws_size,
                              hipStream_t stream) {
    const float* x = (const float*)d_in[0];
    const float* W = (const float*)d_in[1];
    float* out = (float*)d_out;

    const size_t vbytes = (size_t)B_ * C_ * E_ * sizeof(float);  // 40 KB
    float* v_cum = (float*)d_ws;
    float* partial = (float*)((char*)d_ws + vbytes);

    int NBLK = 256;  // blocks; 2 slots per block
    while (NBLK > 1 &&
           vbytes + (size_t)(2 * NBLK) * B_ * C_ * E_ * sizeof(float) > ws_size)
        NBLK >>= 1;
    const int NS = 2 * NBLK;
    const int np = N_ / NS;  // n per wave

    for (int t = 0; t < 3; ++t) {
        if (t == 0)
            caps_pass<true><<<dim3(NBLK), 512, 0, stream>>>(x, W, v_cum, partial, np);
        else
            caps_pass<false><<<dim3(NBLK), 512, 0, stream>>>(x, W, v_cum, partial, np);
        caps_reduce<<<dim3(B_), 512, 0, stream>>>(partial, v_cum, out, NS, t);
    }
}

// Round 4
// 336.085 us; speedup vs baseline: 1.6251x; 1.6251x over previous
//
#include <hip/hip_runtime.h>

#define B_ 64
#define N_ 4096
#define C_ 10
#define D_ 8
#define E_ 16
#define EPS_ 1e-7f
#define NT_ 8                 // n per block
#define NBLK_ (N_ / NT_)      // 512 blocks = 512 partial slots

__device__ inline float reduce16(float v) {
    v += __shfl_xor(v, 1);
    v += __shfl_xor(v, 2);
    v += __shfl_xor(v, 4);
    v += __shfl_xor(v, 8);
    return v;
}

// Block: 512 threads = 8 waves = 4 b-quarters (q) x 2 n-halves (h).
// Lane: eq = lane&3 (e-quad), bl = lane>>2; b = q*16+bl.
// W tile for the block's 8 n staged in LDS (40KB); compute reads are
// ds_read_b128 broadcasts (4 unique addrs/instr, conflict-free).
template <bool UNIFORM>
__global__ __launch_bounds__(512, 4) void caps_pass(
    const float* __restrict__ x, const float* __restrict__ W,
    const float* __restrict__ v_cum, float* __restrict__ partial)
{
    __shared__ float wtile[NT_ * C_ * D_ * E_];   // 10240 floats = 40KB

    const int tid = (int)threadIdx.x;
    const int n0  = (int)blockIdx.x * NT_;

    // ---- stage W[n0..n0+8) -> LDS, coalesced float4 ----
    {
        const float4* gsrc = (const float4*)(W + (size_t)n0 * (C_ * D_ * E_));
        float4* ldst = (float4*)wtile;
#pragma unroll
        for (int it = 0; it < 5; ++it)
            ldst[it * 512 + tid] = gsrc[it * 512 + tid];
    }
    __syncthreads();

    const int w    = tid >> 6;
    const int lane = tid & 63;
    const int eq   = lane & 3;
    const int bl   = lane >> 2;
    const int q    = w & 3;
    const int h    = w >> 2;
    const int b    = q * 16 + bl;

    const float* vbase = v_cum + ((size_t)b * C_) * E_ + eq * 4;

    float4 acc[C_];
#pragma unroll
    for (int c = 0; c < C_; ++c) acc[c] = make_float4(0.f, 0.f, 0.f, 0.f);

#pragma unroll
    for (int j = 0; j < NT_ / 2; ++j) {      // 4 n per wave
        const int nl = h * (NT_ / 2) + j;
        const int n  = n0 + nl;

        const float4* xp = (const float4*)(x + ((size_t)b * N_ + n) * D_);
        const float4 x0 = xp[0], x1 = xp[1];
        const float xv[D_] = {x0.x, x0.y, x0.z, x0.w, x1.x, x1.y, x1.z, x1.w};

        const float4* wl = (const float4*)(wtile + nl * (C_ * D_ * E_)) + eq;

        float4 uh[C_];
#pragma unroll
        for (int c = 0; c < C_; ++c) {
            float4 u = make_float4(0.f, 0.f, 0.f, 0.f);
#pragma unroll
            for (int d = 0; d < D_; ++d) {
                const float4 wq = wl[(c * D_ + d) * 4];
                u.x = fmaf(xv[d], wq.x, u.x);
                u.y = fmaf(xv[d], wq.y, u.y);
                u.z = fmaf(xv[d], wq.z, u.z);
                u.w = fmaf(xv[d], wq.w, u.w);
            }
            uh[c] = u;
        }

        float wgt[C_];
        if (UNIFORM) {
#pragma unroll
            for (int c = 0; c < C_; ++c) wgt[c] = 0.1f;
        } else {
            float logit[C_];
#pragma unroll
            for (int c = 0; c < C_; ++c) {
                const float4 vc = *(const float4*)(vbase + c * E_);
                float t = uh[c].x * vc.x + uh[c].y * vc.y +
                          uh[c].z * vc.z + uh[c].w * vc.w;
                t += __shfl_xor(t, 1);
                t += __shfl_xor(t, 2);
                logit[c] = t;
            }
            float m = logit[0];
#pragma unroll
            for (int c = 1; c < C_; ++c) m = fmaxf(m, logit[c]);
            float ss = 0.f;
#pragma unroll
            for (int c = 0; c < C_; ++c) { wgt[c] = __expf(logit[c] - m); ss += wgt[c]; }
            const float inv = 1.f / ss;
#pragma unroll
            for (int c = 0; c < C_; ++c) wgt[c] *= inv;
        }

#pragma unroll
        for (int c = 0; c < C_; ++c) {
            acc[c].x = fmaf(wgt[c], uh[c].x, acc[c].x);
            acc[c].y = fmaf(wgt[c], uh[c].y, acc[c].y);
            acc[c].z = fmaf(wgt[c], uh[c].z, acc[c].z);
            acc[c].w = fmaf(wgt[c], uh[c].w, acc[c].w);
        }
    }

    // ---- combine the two n-halves via LDS (overlay dead W tile) ----
    __syncthreads();
    float* comb = wtile;   // [b][c][e] = b*160 + c*16 + e
    if (h == 1) {
        float* dst = comb + b * (C_ * E_) + eq * 4;
#pragma unroll
        for (int c = 0; c < C_; ++c) *(float4*)(dst + c * E_) = acc[c];
    }
    __syncthreads();
    if (h == 0) {
        const float* src = comb + b * (C_ * E_) + eq * 4;
        float* pdst = partial + ((size_t)blockIdx.x * B_ + b) * (C_ * E_) + eq * 4;
#pragma unroll
        for (int c = 0; c < C_; ++c) {
            const float4 o = *(const float4*)(src + c * E_);
            float4 r;
            r.x = acc[c].x + o.x; r.y = acc[c].y + o.y;
            r.z = acc[c].z + o.z; r.w = acc[c].w + o.w;
            *(float4*)(pdst + c * E_) = r;
        }
    }
}

// Block per b: sum partials over NS slots, squash, write v_cum/out.
// mode: 0 = v_cum = v (first), 1 = v_cum += v, 2 = out = v (last)
__global__ __launch_bounds__(512) void caps_reduce(
    const float* __restrict__ partial, float* __restrict__ v_cum,
    float* __restrict__ out, int NS, int mode)
{
    const int b = (int)blockIdx.x;
    const int tid = (int)threadIdx.x;
    const int half = tid >> 8;
    const int ce = tid & 255;
    __shared__ float red[2][C_ * E_];
    if (ce < C_ * E_) {
        const int per = NS >> 1;
        float s = 0.f;
        for (int k = 0; k < per; ++k) {
            const int slot = half * per + k;
            s += partial[((size_t)slot * B_ + b) * (C_ * E_) + ce];
        }
        red[half][ce] = s;
    }
    __syncthreads();
    if (half == 0 && ce < C_ * E_) {
        float s = red[0][ce] + red[1][ce];
        const float s2 = reduce16(s * s);
        const float scale = (s2 / (1.f + s2)) * rsqrtf(s2 + EPS_);
        const float v = scale * s;
        if (mode == 2)      out[b * (C_ * E_) + ce] = v;
        else if (mode == 0) v_cum[b * (C_ * E_) + ce] = v;
        else                v_cum[b * (C_ * E_) + ce] += v;
    }
}

extern "C" void kernel_launch(void* const* d_in, const int* in_sizes, int n_in,
                              void* d_out, int out_size, void* d_ws, size_t ws_size,
                              hipStream_t stream) {
    const float* x = (const float*)d_in[0];
    const float* W = (const float*)d_in[1];
    float* out = (float*)d_out;

    const size_t vbytes = (size_t)B_ * C_ * E_ * sizeof(float);  // 40 KB
    float* v_cum = (float*)d_ws;
    float* partial = (float*)((char*)d_ws + vbytes);

    for (int t = 0; t < 3; ++t) {
        if (t == 0)
            caps_pass<true><<<dim3(NBLK_), 512, 0, stream>>>(x, W, v_cum, partial);
        else
            caps_pass<false><<<dim3(NBLK_), 512, 0, stream>>>(x, W, v_cum, partial);
        caps_reduce<<<dim3(B_), 512, 0, stream>>>(partial, v_cum, out, NBLK_, t);
    }
}

// Round 5
// 234.453 us; speedup vs baseline: 2.3295x; 1.4335x over previous
//
#include <hip/hip_runtime.h>

#define B_ 64
#define N_ 4096
#define C_ 10
#define D_ 8
#define E_ 16
#define EPS_ 1e-7f

__device__ inline float reduce16(float v) {
    v += __shfl_xor(v, 1);
    v += __shfl_xor(v, 2);
    v += __shfl_xor(v, 4);
    v += __shfl_xor(v, 8);
    return v;
}

// Block: 256 threads = 4 waves = 4 b-quarters. Each wave processes all NT n
// for its 16 b. Lane: eq = lane&3 (e-quad), bl = lane>>2, b = q*16+bl.
// W tile for NT n staged in LDS; compute reads are ds_read_b128 broadcasts.
// Partial layout [b][slot][ce] so the reduce streams coalesced.
template <int NT, bool UNIFORM>
__global__ __launch_bounds__(256, 4) void caps_pass(
    const float* __restrict__ x, const float* __restrict__ W,
    const float* __restrict__ v_cum, float* __restrict__ partial,
    int NSLOT)
{
    __shared__ float wtile[NT * C_ * D_ * E_];   // NT*1280 floats

    const int tid  = (int)threadIdx.x;
    const int slot = (int)blockIdx.x;
    const int n0   = slot * NT;

    // ---- stage W[n0..n0+NT) -> LDS, coalesced float4 ----
    {
        const float4* gsrc = (const float4*)(W + (size_t)n0 * (C_ * D_ * E_));
        float4* ldst = (float4*)wtile;
        constexpr int LD4 = (NT * 320) / 256;   // float4 per thread
#pragma unroll
        for (int it = 0; it < LD4; ++it)
            ldst[it * 256 + tid] = gsrc[it * 256 + tid];
    }
    __syncthreads();

    const int q    = tid >> 6;
    const int lane = tid & 63;
    const int eq   = lane & 3;
    const int bl   = lane >> 2;
    const int b    = q * 16 + bl;

    const float* vbase = v_cum + (size_t)b * (C_ * E_) + eq * 4;

    float4 acc[C_];
#pragma unroll
    for (int c = 0; c < C_; ++c) acc[c] = make_float4(0.f, 0.f, 0.f, 0.f);

    for (int i = 0; i < NT; ++i) {
        const int n = n0 + i;
        const float4* xp = (const float4*)(x + ((size_t)b * N_ + n) * D_);
        const float4 x0 = xp[0], x1 = xp[1];
        const float xv[D_] = {x0.x, x0.y, x0.z, x0.w, x1.x, x1.y, x1.z, x1.w};

        const float4* wl = (const float4*)(wtile + i * (C_ * D_ * E_)) + eq;

        float4 uh[C_];
#pragma unroll
        for (int c = 0; c < C_; ++c) {
            float4 u = make_float4(0.f, 0.f, 0.f, 0.f);
#pragma unroll
            for (int d = 0; d < D_; ++d) {
                const float4 wq = wl[(c * D_ + d) * 4];
                u.x = fmaf(xv[d], wq.x, u.x);
                u.y = fmaf(xv[d], wq.y, u.y);
                u.z = fmaf(xv[d], wq.z, u.z);
                u.w = fmaf(xv[d], wq.w, u.w);
            }
            uh[c] = u;
        }

        float wgt[C_];
        if (UNIFORM) {
#pragma unroll
            for (int c = 0; c < C_; ++c) wgt[c] = 0.1f;
        } else {
            float logit[C_];
#pragma unroll
            for (int c = 0; c < C_; ++c) {
                const float4 vc = *(const float4*)(vbase + c * E_);
                float t = uh[c].x * vc.x + uh[c].y * vc.y +
                          uh[c].z * vc.z + uh[c].w * vc.w;
                t += __shfl_xor(t, 1);
                t += __shfl_xor(t, 2);
                logit[c] = t;
            }
            float m = logit[0];
#pragma unroll
            for (int c = 1; c < C_; ++c) m = fmaxf(m, logit[c]);
            float ss = 0.f;
#pragma unroll
            for (int c = 0; c < C_; ++c) { wgt[c] = __expf(logit[c] - m); ss += wgt[c]; }
            const float inv = 1.f / ss;
#pragma unroll
            for (int c = 0; c < C_; ++c) wgt[c] *= inv;
        }

#pragma unroll
        for (int c = 0; c < C_; ++c) {
            acc[c].x = fmaf(wgt[c], uh[c].x, acc[c].x);
            acc[c].y = fmaf(wgt[c], uh[c].y, acc[c].y);
            acc[c].z = fmaf(wgt[c], uh[c].z, acc[c].z);
            acc[c].w = fmaf(wgt[c], uh[c].w, acc[c].w);
        }
    }

    // partial[b][slot][ce], 64B chunks per (c, 4eq)
    float* pdst = partial + ((size_t)b * NSLOT + slot) * (C_ * E_) + eq * 4;
#pragma unroll
    for (int c = 0; c < C_; ++c)
        *(float4*)(pdst + c * E_) = acc[c];
}

// Block per b: 512 threads = 2 slot-halves x 256 (160 active ce each).
// Streams partial[b][k][ce] rows (640B contiguous per k), 4-way unroll.
// mode: 0 = v_cum = v, 1 = v_cum += v, 2 = out = v
__global__ __launch_bounds__(512) void caps_reduce(
    const float* __restrict__ partial, float* __restrict__ v_cum,
    float* __restrict__ out, int NSLOT, int mode)
{
    const int b = (int)blockIdx.x;
    const int tid = (int)threadIdx.x;
    const int half = tid >> 8;
    const int ce = tid & 255;
    __shared__ float red[2][C_ * E_];
    if (ce < C_ * E_) {
        const int cnt = NSLOT >> 1;
        const float* base = partial +
            ((size_t)b * NSLOT + (size_t)half * cnt) * (C_ * E_) + ce;
        float s0 = 0.f, s1 = 0.f, s2 = 0.f, s3 = 0.f;
        for (int k = 0; k < cnt; k += 4) {
            s0 += base[(size_t)(k + 0) * (C_ * E_)];
            s1 += base[(size_t)(k + 1) * (C_ * E_)];
            s2 += base[(size_t)(k + 2) * (C_ * E_)];
            s3 += base[(size_t)(k + 3) * (C_ * E_)];
        }
        red[half][ce] = (s0 + s1) + (s2 + s3);
    }
    __syncthreads();
    if (tid < C_ * E_) {
        float s = red[0][tid] + red[1][tid];
        const float s2 = reduce16(s * s);
        const float scale = (s2 / (1.f + s2)) * rsqrtf(s2 + EPS_);
        const float v = scale * s;
        if (mode == 2)      out[b * (C_ * E_) + tid] = v;
        else if (mode == 0) v_cum[b * (C_ * E_) + tid] = v;
        else                v_cum[b * (C_ * E_) + tid] += v;
    }
}

extern "C" void kernel_launch(void* const* d_in, const int* in_sizes, int n_in,
                              void* d_out, int out_size, void* d_ws, size_t ws_size,
                              hipStream_t stream) {
    const float* x = (const float*)d_in[0];
    const float* W = (const float*)d_in[1];
    float* out = (float*)d_out;

    const size_t vbytes = (size_t)B_ * C_ * E_ * sizeof(float);  // 40 KB
    float* v_cum = (float*)d_ws;
    float* partial = (float*)((char*)d_ws + vbytes);

    // Prefer 1024 slots (NT=4, better occupancy) if ws fits; else proven 512.
    const size_t need1024 = vbytes + (size_t)1024 * B_ * C_ * E_ * sizeof(float);
    const bool big = (ws_size >= need1024);
    const int NSLOT = big ? 1024 : 512;

    for (int t = 0; t < 3; ++t) {
        if (big) {
            if (t == 0) caps_pass<4, true ><<<dim3(NSLOT), 256, 0, stream>>>(x, W, v_cum, partial, NSLOT);
            else        caps_pass<4, false><<<dim3(NSLOT), 256, 0, stream>>>(x, W, v_cum, partial, NSLOT);
        } else {
            if (t == 0) caps_pass<8, true ><<<dim3(NSLOT), 256, 0, stream>>>(x, W, v_cum, partial, NSLOT);
            else        caps_pass<8, false><<<dim3(NSLOT), 256, 0, stream>>>(x, W, v_cum, partial, NSLOT);
        }
        caps_reduce<<<dim3(B_), 512, 0, stream>>>(partial, v_cum, out, NSLOT, t);
    }
}